// Round 4
// baseline (440.974 us; speedup 1.0000x reference)
//
#include <hip/hip_runtime.h>
#include <hip/hip_bf16.h>
#include <math.h>

// ---------------- problem constants ----------------
#define A_    32
#define B_    32
#define PS    16
#define KK_   9
#define KKA_  288      // KK_*A_
#define OH_   7
#define L_    49
#define NB    4
#define NSITE 196      // NB*L_

#define LAM1 5.0e-4f        // 0.01*(1-0.95^1)
#define LAM2 9.75e-4f       // 0.01*(1-0.95^2)
#define LAM3 1.42625e-3f    // 0.01*(1-0.95^3)
#define LOG_LN2PI 0.6086775903077413f  // log(log(2*pi))

typedef _Float16 half4 __attribute__((ext_vector_type(4)));

// clamp that also absorbs NaN under IEEE fminf/fmaxf
static __device__ __forceinline__ float san(float x, float lo, float hi){
    return fminf(fmaxf(x, lo), hi);
}

// ================= K1: filter kernel c'_p from freq_w (fp32 in) =================
__global__ void k_prep_c(const float* __restrict__ fw,
                         float* __restrict__ cprime, float* __restrict__ csum)
{
    int id = blockIdx.x*256 + threadIdx.x;
    if (id >= 16*288) return;
    int p = id / 288, m = id % 288;
    // c2r irfft ignores imag of DC/Nyquist bins; ortho norms cancel to 1/N
    float acc = fw[(0*16 + p)*2 + 0];                 // Re W0
    for (int k = 1; k <= 143; ++k){
        float re = fw[(k*16 + p)*2 + 0];
        float im = fw[(k*16 + p)*2 + 1];
        int km = (k*m) % 288;
        float ang = 0.021816615649929116f * (float)km;  // 2*pi/288
        float s, c; sincosf(ang, &s, &c);
        acc += 2.0f*(re*c - im*s);
    }
    float re144 = fw[(144*16 + p)*2 + 0];
    acc += re144 * ((m & 1) ? -1.0f : 1.0f);
    float cv = acc * (1.0f/288.0f);
    if (m == 0) cv += 1.0f;                            // + identity (residual)
    cprime[p*288 + m] = san(cv, -1e4f, 1e4f);
    if (m == 0) csum[p] = san(1.0f + fw[(0*16 + p)*2 + 0], -1e4f, 1e4f);
}

// ================= K2: unfold pose -> Xg (bf16), one site-group =================
__global__ void k_prep_x(const float* __restrict__ pose,
                         __hip_bfloat16* __restrict__ Xg, int n0, int cols)
{
    int id = blockIdx.x*256 + threadIdx.x;
    if (id >= KKA_*cols) return;
    int j = id / cols, c = id % cols;
    int n = n0 + (c >> 4), q = c & 15;
    int bs = n / L_, l = n % L_, oy = l / OH_, ox = l % OH_;
    int kk = j >> 5, a = j & 31;
    int ki = kk / 3, kj = kk % 3;
    int y = oy*2 - 1 + ki, x = ox*2 - 1 + kj;
    float v = 0.f;
    if ((unsigned)y < 14u && (unsigned)x < 14u)
        v = pose[((bs*(A_*PS) + a*PS + q)*14 + y)*14 + x];
    Xg[j*cols + c] = __float2bfloat16(san(v, -1e4f, 1e4f));
}

// ================= K3: U_p = (I + C_p) @ Xg, fp16 out, one group =================
__launch_bounds__(256)
__global__ void k_stageB(const float* __restrict__ cprime, const __hip_bfloat16* __restrict__ Xg,
                         _Float16* __restrict__ U, int cols, int ns)
{
    const int bx = blockIdx.x, by = blockIdx.y, p = blockIdx.z;
    const int t = threadIdx.x;
    const int tx = t & 15, ty = t >> 4;
    __shared__ float As[16][48];
    __shared__ float Bs[16][64];
    const float* cp = cprime + p*288;
    const int i0 = by*48, c0 = bx*64;
    float acc[3][4] = {{0.f,0.f,0.f,0.f},{0.f,0.f,0.f,0.f},{0.f,0.f,0.f,0.f}};

    for (int k0 = 0; k0 < 288; k0 += 16){
        for (int e = t; e < 768; e += 256){
            int k = e / 48, ii = e % 48;
            int d = (i0 + ii) - (k0 + k);
            if (d < 0) d += 288;
            As[k][ii] = cp[d];
        }
        {
            int k = t >> 4, cc = (t & 15) << 2;
            int c = c0 + cc;
            float4 bv = make_float4(0.f, 0.f, 0.f, 0.f);
            if (c < cols){
                ushort4 u4 = *(const ushort4*)&Xg[(k0 + k)*cols + c];
                bv.x = __uint_as_float(((unsigned)u4.x) << 16);
                bv.y = __uint_as_float(((unsigned)u4.y) << 16);
                bv.z = __uint_as_float(((unsigned)u4.z) << 16);
                bv.w = __uint_as_float(((unsigned)u4.w) << 16);
            }
            *(float4*)&Bs[k][cc] = bv;
        }
        __syncthreads();
        #pragma unroll
        for (int k = 0; k < 16; ++k){
            float a0 = As[k][ty*3+0], a1 = As[k][ty*3+1], a2 = As[k][ty*3+2];
            float4 b = *(const float4*)&Bs[k][tx*4];
            acc[0][0] += a0*b.x; acc[0][1] += a0*b.y; acc[0][2] += a0*b.z; acc[0][3] += a0*b.w;
            acc[1][0] += a1*b.x; acc[1][1] += a1*b.y; acc[1][2] += a1*b.z; acc[1][3] += a1*b.w;
            acc[2][0] += a2*b.x; acc[2][1] += a2*b.y; acc[2][2] += a2*b.z; acc[2][3] += a2*b.w;
        }
        __syncthreads();
    }
    const int col = c0 + tx*4;
    if (col < cols){
        const int nn = col >> 4, q0 = col & 15;   // local site, q
        #pragma unroll
        for (int r = 0; r < 3; ++r){
            int i = i0 + ty*3 + r;
            half4 o;
            o.x = (_Float16)acc[r][0]; o.y = (_Float16)acc[r][1];
            o.z = (_Float16)acc[r][2]; o.w = (_Float16)acc[r][3];
            *(half4*)&U[(i*ns + nn)*256 + p*16 + q0] = o;
        }
    }
}

// ================= K4: v = U.W2^T + bias, 3 fused EM iterations, one group =================
__launch_bounds__(512)
__global__ void k_em(const _Float16* __restrict__ U, const float* __restrict__ a_in,
                     const float* __restrict__ mpw, const float* __restrict__ mpb,
                     const float* __restrict__ csum,
                     const float* __restrict__ beta_u, const float* __restrict__ beta_a,
                     int n0, int ns, float* __restrict__ out)
{
    const int nl = blockIdx.x;          // local site in group
    const int n  = n0 + nl;             // global site
    const int t = threadIdx.x;          // 512
    const int Bc = t >> 4, p = t & 15;  // thread = (Bc, p)
    const int bs = n / L_, l = n % L_;

    __shared__ float a_s[KKA_];
    __shared__ float shv[10240];        // us chunk [16][16][20] (first 5120) / vs chunk [16][32*20]
    __shared__ float mu_s[640], i2s_s[640];
    __shared__ float rbuf[16*33];
    __shared__ float cst[32];

    // unfold this site's activation row directly from a_in
    for (int j = t; j < KKA_; j += 512){
        int kk = j >> 5, a = j & 31;
        int oy = l / OH_, ox = l % OH_;
        int y = oy*2 - 1 + kk/3, x = ox*2 - 1 + kk%3;
        float v = 0.f;
        if ((unsigned)y < 14u && (unsigned)x < 14u)
            v = a_in[((bs*A_ + a)*14 + y)*14 + x];
        a_s[j] = san(v, 0.f, 1e4f);
    }
    float w[16];
    #pragma unroll
    for (int q = 0; q < 16; ++q) w[q] = san(mpw[t*16 + q], -1e4f, 1e4f);
    const float b2 = san(mpb[t], -1e4f, 1e4f);
    const float vb = b2 * csum[p];      // bias pushed through the filter
    const float bu = san(beta_u[Bc], -1e4f, 1e4f);
    const float ba = san(beta_a[Bc], -1e4f, 1e4f);
    __syncthreads();

    float S0tot = 0.f;
    for (int j = 0; j < KKA_; ++j) S0tot += a_s[j];   // broadcast reads

    // ---- phase 1: v on the fly + iter-1 moments (r = 1/32 exactly) ----
    float S1 = 0.f, S2 = 0.f;
    for (int ic = 0; ic < 18; ++ic){
        const int i0 = ic*16;
        #pragma unroll
        for (int r = 0; r < 2; ++r){
            int g = t + r*512;               // 0..1023 half4-groups
            int ii = g >> 6, e4 = g & 63;
            half4 h = *(const half4*)&U[((i0+ii)*ns + nl)*256 + e4*4];
            int pld = e4 >> 2, qld = (e4 & 3) << 2;
            float4 f = make_float4((float)h.x, (float)h.y, (float)h.z, (float)h.w);
            *(float4*)&shv[(ii*16 + pld)*20 + qld] = f;
        }
        __syncthreads();
        #pragma unroll
        for (int ii = 0; ii < 16; ++ii){
            const float* us = &shv[(ii*16 + p)*20];
            float v = vb;
            #pragma unroll
            for (int q = 0; q < 16; q += 4){
                float4 uq = *(const float4*)&us[q];
                v += uq.x*w[q] + uq.y*w[q+1] + uq.z*w[q+2] + uq.w*w[q+3];
            }
            v = san(v, -1e4f, 1e4f);
            const float au = a_s[i0 + ii];
            S1 += au*v; S2 += au*v*v;
        }
        __syncthreads();
    }
    // iter-1 stats: rr = a_u/32
    {
        const float rs  = S0tot * (1.0f/32.0f);
        const float inv = 1.0f / (rs + 1e-12f);
        const float S1r = S1 * (1.0f/32.0f), S2r = S2 * (1.0f/32.0f);
        const float mu  = san(S1r * inv, -1e4f, 1e4f);
        const float sg  = fmaxf((S2r - 2.f*mu*S1r + mu*mu*rs) * inv, 0.f) + 1e-12f;
        const float lg  = logf(sg);
        float cs = (bu + 0.5f*lg) * rs;       // cost_p
        float ls = lg + LOG_LN2PI;            // log(sig*LN2PI)
        #pragma unroll
        for (int m = 1; m < 16; m <<= 1){ cs += __shfl_xor(cs, m, 16); ls += __shfl_xor(ls, m, 16); }
        const float aout = san(1.f/(1.f + expf(-LAM1*(ba - cs))), 1e-30f, 1.f);
        mu_s[Bc*20 + p] = mu; i2s_s[Bc*20 + p] = 0.5f/sg;
        if (p == 0) cst[Bc] = logf(aout) - 0.5f*ls;
    }
    __syncthreads();

    // ---- iterations 2,3: recompute v from U, fused e-step + m-step ----
    const float lamv[2] = {LAM2, LAM3};
    float muF = 0.f, aF = 0.f;
    for (int it = 0; it < 2; ++it){
        float T0 = 0.f, T1 = 0.f, T2 = 0.f;
        for (int ch = 0; ch < 18; ++ch){
            const int i0 = ch*16;
            // (a) load U chunk -> us (shv[0..5120))
            #pragma unroll
            for (int r = 0; r < 2; ++r){
                int g = t + r*512;
                int ii = g >> 6, e4 = g & 63;
                half4 h = *(const half4*)&U[((i0+ii)*ns + nl)*256 + e4*4];
                int pld = e4 >> 2, qld = (e4 & 3) << 2;
                float4 f = make_float4((float)h.x, (float)h.y, (float)h.z, (float)h.w);
                *(float4*)&shv[(ii*16 + pld)*20 + qld] = f;
            }
            __syncthreads();                       // (1) us ready
            // (b) recompute v for this thread's (Bc,p), all 16 i
            float vreg[16];
            #pragma unroll
            for (int ii = 0; ii < 16; ++ii){
                const float* us = &shv[(ii*16 + p)*20];
                float v = vb;
                #pragma unroll
                for (int q = 0; q < 16; q += 4){
                    float4 uq = *(const float4*)&us[q];
                    v += uq.x*w[q] + uq.y*w[q+1] + uq.z*w[q+2] + uq.w*w[q+3];
                }
                vreg[ii] = san(v, -1e4f, 1e4f);
            }
            __syncthreads();                       // (2) all done reading us
            // (c) publish vs chunk [ii][Bc][p] (clobbers us region)
            #pragma unroll
            for (int ii = 0; ii < 16; ++ii)
                shv[ii*640 + Bc*20 + p] = vreg[ii];
            __syncthreads();                       // (3) vs ready
            // (d) e-step: thread -> (isub, Bce)
            {
                const int isub = t >> 5, Bce = t & 31;
                const float* vrow = &shv[isub*640 + Bce*20];
                const float* mrow = &mu_s[Bce*20];
                const float* srow = &i2s_s[Bce*20];
                float ds = 0.f;
                #pragma unroll
                for (int q = 0; q < 16; q += 4){
                    float4 vq = *(const float4*)&vrow[q];
                    float4 mq = *(const float4*)&mrow[q];
                    float4 sq = *(const float4*)&srow[q];
                    float d0 = vq.x-mq.x, d1 = vq.y-mq.y, d2 = vq.z-mq.z, d3 = vq.w-mq.w;
                    ds += d0*d0*sq.x + d1*d1*sq.y + d2*d2*sq.z + d3*d3*sq.w;
                }
                float lnap = cst[Bce] - ds;
                float mx = lnap;
                #pragma unroll
                for (int m = 16; m >= 1; m >>= 1) mx = fmaxf(mx, __shfl_xor(mx, m, 32));
                float ex = expf(lnap - mx);
                float sum = ex;
                #pragma unroll
                for (int m = 16; m >= 1; m >>= 1) sum += __shfl_xor(sum, m, 32);
                rbuf[isub*33 + Bce] = (ex / sum) * a_s[i0 + isub];
            }
            __syncthreads();                       // (4) rbuf ready; vs reads done
            // (e) accumulate moments from registers
            #pragma unroll
            for (int ii = 0; ii < 16; ++ii){
                float rr = rbuf[ii*33 + Bc];
                float vv = vreg[ii];
                T0 += rr; T1 += rr*vv; T2 += rr*vv*vv;
            }
        }
        const float inv = 1.f/(T0 + 1e-12f);
        const float mu  = san(T1 * inv, -1e4f, 1e4f);
        const float sg  = fmaxf((T2 - 2.f*mu*T1 + mu*mu*T0) * inv, 0.f) + 1e-12f;
        const float lg  = logf(sg);
        float cs = (bu + 0.5f*lg) * T0;
        float ls = lg + LOG_LN2PI;
        #pragma unroll
        for (int m = 1; m < 16; m <<= 1){ cs += __shfl_xor(cs, m, 16); ls += __shfl_xor(ls, m, 16); }
        const float aout = san(1.f/(1.f + expf(-lamv[it]*(ba - cs))), 1e-30f, 1.f);
        if (it == 0){
            __syncthreads();                       // all accum reads of rbuf done
            mu_s[Bc*20 + p] = mu; i2s_s[Bc*20 + p] = 0.5f/sg;
            if (p == 0) cst[Bc] = logf(aout) - 0.5f*ls;
            __syncthreads();
        } else { muF = mu; aF = aout; }
    }

    // ---- outputs (fp32): [a_fin 4*32*49][pose_out 4*512*49] ----
    if (p == 0) out[bs*(B_*L_) + Bc*L_ + l] = san(aF, 0.f, 1.f);
    out[6272 + (bs*512 + t)*L_ + l] = san(muF, -1e4f, 1e4f);
}

// ================= launch =================
extern "C" void kernel_launch(void* const* d_in, const int* in_sizes, int n_in,
                              void* d_out, int out_size, void* d_ws, size_t ws_size,
                              hipStream_t stream)
{
    // ALL device tensors are float32 (reference is jnp.float32 end-to-end; the
    // "bf16" in the harness label refers to the threshold floor, not storage).
    const float* a_in   = (const float*)d_in[0];
    const float* pose   = (const float*)d_in[1];
    const float* mpw    = (const float*)d_in[2];
    const float* mpb    = (const float*)d_in[3];
    const float* fw     = (const float*)d_in[4];
    // d_in[5..8] (ln_g, ln_b, spat_w, spat_bias) are provably dead: softmax over B of a
    // B-independent gate is exactly 1/B regardless of their values.
    const float* beta_u = (const float*)d_in[9];
    const float* beta_a = (const float*)d_in[10];
    float* out = (float*)d_out;

    // ---- ws layout (byte offsets) ----
    // cprime [16*288] f32 @ 0      (18432 B)
    // csum   [16]     f32 @ 18432  (64 B)
    // Xg  [288*cols] bf16 @ 19456  (9216*ns B, 256-aligned)
    // Ug  [288*ns*256] f16 @ 19456+9216*ns (147456*ns B)
    char* base = (char*)d_ws;
    float* cprime = (float*)(base + 0);
    float* csum   = (float*)(base + 18432);

    // choose largest group size ns (sites per group) fitting ws_size
    const int opts[] = {196, 98, 49, 28, 14, 7, 4, 2, 1};
    int ns = 1;
    for (int oi = 0; oi < 9; ++oi){
        size_t need = 19456u + (size_t)156672u * (size_t)opts[oi];
        if (need <= ws_size){ ns = opts[oi]; break; }
    }
    const int G = NSITE / ns;
    const int cols = ns * PS;
    __hip_bfloat16* Xg = (__hip_bfloat16*)(base + 19456);
    _Float16*       Ug = (_Float16*)(base + 19456 + (size_t)9216*ns);

    k_prep_c<<<18, 256, 0, stream>>>(fw, cprime, csum);
    for (int g = 0; g < G; ++g){
        const int n0 = g * ns;
        k_prep_x<<<(KKA_*cols + 255)/256, 256, 0, stream>>>(pose, Xg, n0, cols);
        k_stageB<<<dim3((cols + 63)/64, 6, 16), 256, 0, stream>>>(cprime, Xg, Ug, cols, ns);
        k_em    <<<ns, 512, 0, stream>>>(Ug, a_in, mpw, mpb, csum, beta_u, beta_a, n0, ns, out);
    }
}

// Round 5
// 376.715 us; speedup vs baseline: 1.1706x; 1.1706x over previous
//
#include <hip/hip_runtime.h>
#include <hip/hip_bf16.h>
#include <math.h>

// ---------------- problem constants ----------------
#define A_    32
#define B_    32
#define PS    16
#define KK_   9
#define KKA_  288      // KK_*A_
#define OH_   7
#define L_    49
#define NB    4
#define NSITE 196      // NB*L_

#define LAM1 5.0e-4f        // 0.01*(1-0.95^1)
#define LAM2 9.75e-4f       // 0.01*(1-0.95^2)
#define LAM3 1.42625e-3f    // 0.01*(1-0.95^3)
#define LOG_LN2PI 0.6086775903077413f  // log(log(2*pi))

typedef _Float16 half2v __attribute__((ext_vector_type(2)));
typedef _Float16 half4v __attribute__((ext_vector_type(4)));

static __device__ __forceinline__ float san(float x, float lo, float hi){
    return fminf(fmaxf(x, lo), hi);
}

static __device__ __forceinline__ float dot2acc(half2v a, half2v b, float c){
#if __has_builtin(__builtin_amdgcn_fdot2)
    return __builtin_amdgcn_fdot2(a, b, c, false);
#else
    return c + (float)a.x*(float)b.x + (float)a.y*(float)b.y;
#endif
}

// ================= K1: filter kernel c'_p from freq_w =================
__global__ void k_prep_c(const float* __restrict__ fw,
                         float* __restrict__ cprime, float* __restrict__ csum)
{
    int id = blockIdx.x*256 + threadIdx.x;
    if (id >= 16*288) return;
    int p = id / 288, m = id % 288;
    // c2r irfft ignores imag of DC/Nyquist bins; ortho norms cancel to 1/N
    float acc = fw[(0*16 + p)*2 + 0];
    for (int k = 1; k <= 143; ++k){
        float re = fw[(k*16 + p)*2 + 0];
        float im = fw[(k*16 + p)*2 + 1];
        int km = (k*m) % 288;
        float ang = 0.021816615649929116f * (float)km;  // 2*pi/288
        float s, c; sincosf(ang, &s, &c);
        acc += 2.0f*(re*c - im*s);
    }
    float re144 = fw[(144*16 + p)*2 + 0];
    acc += re144 * ((m & 1) ? -1.0f : 1.0f);
    float cv = acc * (1.0f/288.0f);
    if (m == 0) cv += 1.0f;                            // + identity (residual)
    cprime[p*288 + m] = san(cv, -1e4f, 1e4f);
    if (m == 0) csum[p] = san(1.0f + fw[(0*16 + p)*2 + 0], -1e4f, 1e4f);
}

// ================= K2: unfold pose -> Xg (bf16), one site-group =================
__global__ void k_prep_x(const float* __restrict__ pose,
                         __hip_bfloat16* __restrict__ Xg, int n0, int cols)
{
    int id = blockIdx.x*256 + threadIdx.x;
    if (id >= KKA_*cols) return;
    int j = id / cols, c = id % cols;
    int n = n0 + (c >> 4), q = c & 15;
    int bs = n / L_, l = n % L_, oy = l / OH_, ox = l % OH_;
    int kk = j >> 5, a = j & 31;
    int y = oy*2 - 1 + kk/3, x = ox*2 - 1 + kk%3;
    float v = 0.f;
    if ((unsigned)y < 14u && (unsigned)x < 14u)
        v = pose[((bs*(A_*PS) + a*PS + q)*14 + y)*14 + x];
    Xg[j*cols + c] = __float2bfloat16(san(v, -1e4f, 1e4f));
}

// ================= K3: U_p = (I + C_p) @ Xg, fp16 out, one group =================
__launch_bounds__(256)
__global__ void k_stageB(const float* __restrict__ cprime, const __hip_bfloat16* __restrict__ Xg,
                         _Float16* __restrict__ U, int cols, int ns)
{
    const int bx = blockIdx.x, by = blockIdx.y, p = blockIdx.z;
    const int t = threadIdx.x;
    const int tx = t & 15, ty = t >> 4;
    __shared__ float As[16][48];
    __shared__ float Bs[16][64];
    const float* cp = cprime + p*288;
    const int i0 = by*48, c0 = bx*64;
    float acc[3][4] = {{0.f,0.f,0.f,0.f},{0.f,0.f,0.f,0.f},{0.f,0.f,0.f,0.f}};

    for (int k0 = 0; k0 < 288; k0 += 16){
        for (int e = t; e < 768; e += 256){
            int k = e / 48, ii = e % 48;
            int d = (i0 + ii) - (k0 + k);
            if (d < 0) d += 288;
            As[k][ii] = cp[d];
        }
        {
            int k = t >> 4, cc = (t & 15) << 2;
            int c = c0 + cc;
            float4 bv = make_float4(0.f, 0.f, 0.f, 0.f);
            if (c < cols){
                ushort4 u4 = *(const ushort4*)&Xg[(k0 + k)*cols + c];
                bv.x = __uint_as_float(((unsigned)u4.x) << 16);
                bv.y = __uint_as_float(((unsigned)u4.y) << 16);
                bv.z = __uint_as_float(((unsigned)u4.z) << 16);
                bv.w = __uint_as_float(((unsigned)u4.w) << 16);
            }
            *(float4*)&Bs[k][cc] = bv;
        }
        __syncthreads();
        #pragma unroll
        for (int k = 0; k < 16; ++k){
            float a0 = As[k][ty*3+0], a1 = As[k][ty*3+1], a2 = As[k][ty*3+2];
            float4 b = *(const float4*)&Bs[k][tx*4];
            acc[0][0] += a0*b.x; acc[0][1] += a0*b.y; acc[0][2] += a0*b.z; acc[0][3] += a0*b.w;
            acc[1][0] += a1*b.x; acc[1][1] += a1*b.y; acc[1][2] += a1*b.z; acc[1][3] += a1*b.w;
            acc[2][0] += a2*b.x; acc[2][1] += a2*b.y; acc[2][2] += a2*b.z; acc[2][3] += a2*b.w;
        }
        __syncthreads();
    }
    const int col = c0 + tx*4;
    if (col < cols){
        const int nn = col >> 4, q0 = col & 15;   // local site, q
        #pragma unroll
        for (int r = 0; r < 3; ++r){
            int i = i0 + ty*3 + r;
            half4v o;
            o.x = (_Float16)acc[r][0]; o.y = (_Float16)acc[r][1];
            o.z = (_Float16)acc[r][2]; o.w = (_Float16)acc[r][3];
            *(half4v*)&U[(i*ns + nn)*256 + p*16 + q0] = o;
        }
    }
}

// ================= K4: v in registers + 3 fused EM iterations =================
__launch_bounds__(512, 2)
__global__ void k_em(const _Float16* __restrict__ U, const float* __restrict__ a_in,
                     const float* __restrict__ mpw, const float* __restrict__ mpb,
                     const float* __restrict__ csum,
                     const float* __restrict__ beta_u, const float* __restrict__ beta_a,
                     int n0, int ns, float* __restrict__ out)
{
    const int nl = blockIdx.x;          // local site in group
    const int n  = n0 + nl;             // global site
    const int t = threadIdx.x;          // 512
    const int Bc = t >> 4, p = t & 15;  // thread = (Bc, p)
    const int bs = n / L_, l = n % L_;

    __shared__ _Float16 us[2][16][256]; // staging chunk: [buf][ii][p*16+q]
    __shared__ float a_s[KKA_];
    __shared__ float d_s[16][33];
    __shared__ float rbuf[16][33];
    __shared__ float cst[32];

    // issue U chunk-0 loads first (longest latency)
    half4v ha, hb;
    {
        int u0 = t, u1 = t + 512;
        ha = *(const half4v*)&U[((u0>>6)*ns + nl)*256 + (u0&63)*4];
        hb = *(const half4v*)&U[((8 + (u1&511)/64)*ns + nl)*256 + (u1&63)*4];
    }

    // unfold this site's activation row
    for (int j = t; j < KKA_; j += 512){
        int kk = j >> 5, a = j & 31;
        int oy = l / OH_, ox = l % OH_;
        int y = oy*2 - 1 + kk/3, x = ox*2 - 1 + kk%3;
        float v = 0.f;
        if ((unsigned)y < 14u && (unsigned)x < 14u)
            v = a_in[((bs*A_ + a)*14 + y)*14 + x];
        a_s[j] = san(v, 0.f, 1e4f);
    }
    // per-thread weight row as packed fp16
    half2v w_h[8];
    #pragma unroll
    for (int k = 0; k < 8; ++k){
        w_h[k].x = (_Float16)mpw[t*16 + 2*k];
        w_h[k].y = (_Float16)mpw[t*16 + 2*k + 1];
    }
    const float vb = mpb[t] * csum[p];  // bias pushed through the filter
    const float bu = beta_u[Bc];
    const float ba = beta_a[Bc];

    // store chunk 0 into us[0]
    *(half4v*)&us[0][t>>6][(t&63)*4]       = ha;
    *(half4v*)&us[0][8 + (t>>6)][(t&63)*4] = hb;
    __syncthreads();                     // a_s + us[0] ready

    float S0tot = 0.f;
    for (int j = 0; j < KKA_; ++j) S0tot += a_s[j];   // broadcast reads

    // ---- phase 1: v once, banked to 144 packed-fp16 VGPRs; iter-1 moments ----
    half2v v_h[144];
    float S1 = 0.f, S2 = 0.f;
    #pragma unroll
    for (int ch = 0; ch < 18; ++ch){
        if (ch < 17){
            int base = (ch+1)*16;
            int u0 = t, u1 = t + 512;
            ha = *(const half4v*)&U[((base + (u0>>6))*ns + nl)*256 + (u0&63)*4];
            hb = *(const half4v*)&U[((base + 8 + (u0>>6))*ns + nl)*256 + (u1&63)*4];
        }
        #pragma unroll
        for (int k = 0; k < 8; ++k){     // i-pairs (2k, 2k+1)
            union { uint4 u4; half2v h2[4]; } A0, A1, B0, B1;
            A0.u4 = *(const uint4*)&us[ch&1][2*k][p*16];
            A1.u4 = *(const uint4*)&us[ch&1][2*k][p*16 + 8];
            B0.u4 = *(const uint4*)&us[ch&1][2*k+1][p*16];
            B1.u4 = *(const uint4*)&us[ch&1][2*k+1][p*16 + 8];
            float v0 = vb, v1 = vb;
            #pragma unroll
            for (int m = 0; m < 4; ++m){
                v0 = dot2acc(A0.h2[m], w_h[m],   v0);
                v0 = dot2acc(A1.h2[m], w_h[4+m], v0);
                v1 = dot2acc(B0.h2[m], w_h[m],   v1);
                v1 = dot2acc(B1.h2[m], w_h[4+m], v1);
            }
            float a0 = a_s[ch*16 + 2*k], a1 = a_s[ch*16 + 2*k + 1];
            S1 += a0*v0 + a1*v1;
            S2 += a0*v0*v0 + a1*v1*v1;
            half2v vh; vh.x = (_Float16)v0; vh.y = (_Float16)v1;
            v_h[ch*8 + k] = vh;
        }
        if (ch < 17){
            *(half4v*)&us[(ch+1)&1][t>>6][(t&63)*4]       = ha;
            *(half4v*)&us[(ch+1)&1][8 + (t>>6)][(t&63)*4] = hb;
        }
        __syncthreads();
    }

    // iter-1 m-step (r = 1/32 exactly); mu/i2s live in registers
    float mu_r, i2s_r;
    {
        const float rs  = S0tot * (1.0f/32.0f);
        const float inv = 1.0f / (rs + 1e-12f);
        const float S1r = S1 * (1.0f/32.0f), S2r = S2 * (1.0f/32.0f);
        mu_r = S1r * inv;
        const float sg  = fmaxf((S2r - 2.f*mu_r*S1r + mu_r*mu_r*rs) * inv, 0.f) + 1e-12f;
        i2s_r = 0.5f / sg;
        const float lg  = logf(sg);
        float cs = (bu + 0.5f*lg) * rs;
        float ls = lg + LOG_LN2PI;
        #pragma unroll
        for (int m = 1; m < 16; m <<= 1){ cs += __shfl_xor(cs, m, 16); ls += __shfl_xor(ls, m, 16); }
        const float aout = san(1.f/(1.f + expf(-LAM1*(ba - cs))), 1e-30f, 1.f);
        if (p == 0) cst[Bc] = logf(aout) - 0.5f*ls;
    }
    __syncthreads();

    // ---- iterations 2,3: pure-register v; 2 barriers per 16-i chunk ----
    const int b0 = p & 1, b1 = (p>>1)&1, b2 = (p>>2)&1, b3 = (p>>3)&1;
    float muF = 0.f, aF = 0.f;
    for (int it = 0; it < 2; ++it){
        const float lam = it ? LAM3 : LAM2;
        float T0 = 0.f, T1 = 0.f, T2 = 0.f;
        #pragma unroll
        for (int ch = 0; ch < 18; ++ch){
            float vc[16], e[16];
            #pragma unroll
            for (int k = 0; k < 8; ++k){
                half2v vh = v_h[ch*8 + k];
                vc[2*k]   = (float)vh.x;
                vc[2*k+1] = (float)vh.y;
            }
            #pragma unroll
            for (int s = 0; s < 16; ++s){
                float dv = vc[s] - mu_r;
                e[s] = dv*dv*i2s_r;
            }
            // butterfly transpose-reduce over the 16 p-lanes: lane p ends with d(ii=p)
            float e1[8], e2[4], e3[2], dfin;
            #pragma unroll
            for (int s = 0; s < 8; ++s){
                float a  = b0 ? e[2*s+1] : e[2*s];
                float sd = b0 ? e[2*s]   : e[2*s+1];
                e1[s] = a + __shfl_xor(sd, 1);
            }
            #pragma unroll
            for (int s = 0; s < 4; ++s){
                float a  = b1 ? e1[2*s+1] : e1[2*s];
                float sd = b1 ? e1[2*s]   : e1[2*s+1];
                e2[s] = a + __shfl_xor(sd, 2);
            }
            #pragma unroll
            for (int s = 0; s < 2; ++s){
                float a  = b2 ? e2[2*s+1] : e2[2*s];
                float sd = b2 ? e2[2*s]   : e2[2*s+1];
                e3[s] = a + __shfl_xor(sd, 4);
            }
            {
                float a  = b3 ? e3[1] : e3[0];
                float sd = b3 ? e3[0] : e3[1];
                dfin = a + __shfl_xor(sd, 8);
            }
            d_s[p][Bc] = dfin;
            __syncthreads();                   // (1) d_s ready
            {   // e-step softmax over B: thread -> (isub, Bce)
                const int isub = t >> 5, Bce = t & 31;
                float lnap = cst[Bce] - d_s[isub][Bce];
                float mx = lnap;
                #pragma unroll
                for (int m = 16; m >= 1; m >>= 1) mx = fmaxf(mx, __shfl_xor(mx, m));
                float ex = expf(lnap - mx);
                float sm = ex;
                #pragma unroll
                for (int m = 16; m >= 1; m >>= 1) sm += __shfl_xor(sm, m);
                rbuf[isub][Bce] = (ex / sm) * a_s[ch*16 + isub];
            }
            __syncthreads();                   // (2) rbuf ready
            #pragma unroll
            for (int s = 0; s < 16; ++s){
                float rr = rbuf[s][Bc];
                float tv = rr * vc[s];
                T0 += rr; T1 += tv; T2 += tv * vc[s];
            }
        }
        // m-step
        const float inv = 1.f/(T0 + 1e-12f);
        const float mu  = T1 * inv;
        const float sg  = fmaxf((T2 - 2.f*mu*T1 + mu*mu*T0) * inv, 0.f) + 1e-12f;
        const float lg  = logf(sg);
        float cs = (bu + 0.5f*lg) * T0;
        float ls = lg + LOG_LN2PI;
        #pragma unroll
        for (int m = 1; m < 16; m <<= 1){ cs += __shfl_xor(cs, m, 16); ls += __shfl_xor(ls, m, 16); }
        const float aout = san(1.f/(1.f + expf(-lam*(ba - cs))), 1e-30f, 1.f);
        if (it == 0){
            mu_r = mu; i2s_r = 0.5f/sg;
            if (p == 0) cst[Bc] = logf(aout) - 0.5f*ls;
            __syncthreads();                   // cst visible before next softmax
        } else { muF = mu; aF = aout; }
    }

    // ---- outputs (fp32): [a_fin 4*32*49][pose_out 4*512*49] ----
    if (p == 0) out[bs*(B_*L_) + Bc*L_ + l] = san(aF, 0.f, 1.f);
    out[6272 + (bs*512 + t)*L_ + l] = san(muF, -1e4f, 1e4f);
}

// ================= launch =================
extern "C" void kernel_launch(void* const* d_in, const int* in_sizes, int n_in,
                              void* d_out, int out_size, void* d_ws, size_t ws_size,
                              hipStream_t stream)
{
    // ALL device tensors are float32 (reference is jnp.float32 end-to-end).
    const float* a_in   = (const float*)d_in[0];
    const float* pose   = (const float*)d_in[1];
    const float* mpw    = (const float*)d_in[2];
    const float* mpb    = (const float*)d_in[3];
    const float* fw     = (const float*)d_in[4];
    // d_in[5..8] (ln_g, ln_b, spat_w, spat_bias) are provably dead: softmax over B of a
    // B-independent gate is exactly 1/B regardless of their values.
    const float* beta_u = (const float*)d_in[9];
    const float* beta_a = (const float*)d_in[10];
    float* out = (float*)d_out;

    // ---- ws layout (byte offsets) ----
    // cprime [16*288] f32 @ 0      (18432 B)
    // csum   [16]     f32 @ 18432  (64 B)
    // Xg  [288*cols] bf16 @ 19456  (9216*ns B)
    // Ug  [288*ns*256] f16 @ 19456+9216*ns (147456*ns B)
    char* base = (char*)d_ws;
    float* cprime = (float*)(base + 0);
    float* csum   = (float*)(base + 18432);

    const int opts[] = {196, 98, 49, 28, 14, 7, 4, 2, 1};
    int ns = 1;
    for (int oi = 0; oi < 9; ++oi){
        size_t need = 19456u + (size_t)156672u * (size_t)opts[oi];
        if (need <= ws_size){ ns = opts[oi]; break; }
    }
    const int G = NSITE / ns;
    const int cols = ns * PS;
    __hip_bfloat16* Xg = (__hip_bfloat16*)(base + 19456);
    _Float16*       Ug = (_Float16*)(base + 19456 + (size_t)9216*ns);

    k_prep_c<<<18, 256, 0, stream>>>(fw, cprime, csum);
    for (int g = 0; g < G; ++g){
        const int n0 = g * ns;
        k_prep_x<<<(KKA_*cols + 255)/256, 256, 0, stream>>>(pose, Xg, n0, cols);
        k_stageB<<<dim3((cols + 63)/64, 6, 16), 256, 0, stream>>>(cprime, Xg, Ug, cols, ns);
        k_em    <<<ns, 512, 0, stream>>>(Ug, a_in, mpw, mpb, csum, beta_u, beta_a, n0, ns, out);
    }
}

// Round 6
// 304.223 us; speedup vs baseline: 1.4495x; 1.2383x over previous
//
#include <hip/hip_runtime.h>
#include <hip/hip_bf16.h>
#include <math.h>

// ---------------- problem constants ----------------
#define A_    32
#define B_    32
#define PS    16
#define KK_   9
#define KKA_  288      // KK_*A_
#define OH_   7
#define L_    49
#define NB    4
#define NSITE 196      // NB*L_

#define LAM1 5.0e-4f        // 0.01*(1-0.95^1)
#define LAM2 9.75e-4f       // 0.01*(1-0.95^2)
#define LAM3 1.42625e-3f    // 0.01*(1-0.95^3)
#define LOG_LN2PI 0.6086775903077413f  // log(log(2*pi))

typedef _Float16 half2v __attribute__((ext_vector_type(2)));
typedef _Float16 half4v __attribute__((ext_vector_type(4)));
typedef short    short8 __attribute__((ext_vector_type(8)));   // 8 bf16 (4 VGPRs)
typedef float    floatx4 __attribute__((ext_vector_type(4)));

static __device__ __forceinline__ float san(float x, float lo, float hi){
    return fminf(fmaxf(x, lo), hi);
}

static __device__ __forceinline__ float dot2acc(half2v a, half2v b, float c){
#if __has_builtin(__builtin_amdgcn_fdot2)
    return __builtin_amdgcn_fdot2(a, b, c, false);
#else
    return c + (float)a.x*(float)b.x + (float)a.y*(float)b.y;
#endif
}

// ================= K1: c'_p filter -> parity-split reversed tables (bf16 hi/lo) =================
// cpr_ext[x] = c'_p[(576 - x) mod 288], x in 0..575 ; cpr1[x] = cpr_ext[x+1]
// A-matrix element A[i][k] = c'[(i-k) mod 288] = cpr_ext[288 + k - i]
__global__ void k_prep_c(const float* __restrict__ fw,
                         ushort* __restrict__ cpr, float* __restrict__ csum)
{
    int id = blockIdx.x*256 + threadIdx.x;
    if (id >= 16*288) return;
    int p = id / 288, m = id % 288;
    // c2r irfft ignores imag of DC/Nyquist bins; ortho norms cancel to 1/N
    float acc = fw[(0*16 + p)*2 + 0];
    for (int k = 1; k <= 143; ++k){
        float re = fw[(k*16 + p)*2 + 0];
        float im = fw[(k*16 + p)*2 + 1];
        int km = (k*m) % 288;
        float ang = 0.021816615649929116f * (float)km;  // 2*pi/288
        float s, c; sincosf(ang, &s, &c);
        acc += 2.0f*(re*c - im*s);
    }
    float re144 = fw[(144*16 + p)*2 + 0];
    acc += re144 * ((m & 1) ? -1.0f : 1.0f);
    float cv = acc * (1.0f/288.0f);
    if (m == 0) cv += 1.0f;                            // + identity (residual)
    cv = san(cv, -1e4f, 1e4f);

    __hip_bfloat16 hb = __float2bfloat16(cv);
    float hif = __bfloat162float(hb);
    __hip_bfloat16 lb = __float2bfloat16(cv - hif);
    ushort hi = *(ushort*)&hb, lo = *(ushort*)&lb;

    ushort* c0h = cpr + p*592;
    ushort* c1h = cpr + 16*592   + p*592;
    ushort* c0l = cpr + 16*592*2 + p*592;
    ushort* c1l = cpr + 16*592*3 + p*592;
    int x1 = 288 - m;                       // covers cpr0[1..288], cpr1[0..287]
    c0h[x1] = hi;  c0l[x1] = lo;
    c1h[x1-1] = hi; c1l[x1-1] = lo;
    if (m >= 1){                            // covers cpr0[289..575], cpr1[288..574]
        int x2 = 576 - m;
        c0h[x2] = hi;  c0l[x2] = lo;
        c1h[x2-1] = hi; c1l[x2-1] = lo;
    } else {                                // cpr0[0] = cpr_ext[0] = c'[0]
        c0h[0] = hi; c0l[0] = lo;
        csum[p] = san(1.0f + fw[(0*16 + p)*2 + 0], -1e4f, 1e4f);
    }
}

// ================= K2: unfold pose -> Xt (bf16, TRANSPOSED [col][j]) =================
__global__ void k_prep_x(const float* __restrict__ pose,
                         __hip_bfloat16* __restrict__ Xt, int n0, int cols)
{
    int id = blockIdx.x*256 + threadIdx.x;
    if (id >= cols*KKA_) return;
    int c = id / KKA_, j = id % KKA_;
    int n = n0 + (c >> 4), q = c & 15;
    int bs = n / L_, l = n % L_, oy = l / OH_, ox = l % OH_;
    int kk = j >> 5, a = j & 31;
    int y = oy*2 - 1 + kk/3, x = ox*2 - 1 + kk%3;
    float v = 0.f;
    if ((unsigned)y < 14u && (unsigned)x < 14u)
        v = pose[((bs*(A_*PS) + a*PS + q)*14 + y)*14 + x];
    Xt[id] = __float2bfloat16(san(v, -1e4f, 1e4f));
}

// ================= K3: U_p = (I + C_p) @ X via bf16 split-MFMA =================
// block: 48 i x 64 cols for one p; 4 waves, wave w owns 16-col slice, 3 i-subtiles.
__launch_bounds__(256)
__global__ void k_stageB(const ushort* __restrict__ cpr, const __hip_bfloat16* __restrict__ Xt,
                         _Float16* __restrict__ U, int cols, int ns)
{
    const int bx = blockIdx.x, by = blockIdx.y, p = blockIdx.z;
    const int t = threadIdx.x;
    const int w = t >> 6, lane = t & 63;
    const int mn = lane & 15, quad = lane >> 4;
    const int i0 = by*48;
    const int col = bx*64 + w*16 + mn;
    const int colc = (col < cols) ? col : (cols - 1);

    const ushort* c0h = cpr + p*592;
    const ushort* c1h = cpr + 16*592   + p*592;
    const ushort* c0l = cpr + 16*592*2 + p*592;
    const ushort* c1l = cpr + 16*592*3 + p*592;

    floatx4 acc[3] = {{0,0,0,0},{0,0,0,0},{0,0,0,0}};
    for (int k0 = 0; k0 < 288; k0 += 32){
        short8 bfrag = *(const short8*)&Xt[colc*KKA_ + k0 + quad*8];
        #pragma unroll
        for (int s = 0; s < 3; ++s){
            // A[m][k] = cpr_ext[288 + k - i], i = i0+s*16+mn, k = k0+quad*8+jj
            int o = 288 + k0 + quad*8 - (i0 + s*16 + mn);
            int sel = o & 1;                 // parity -> pick shifted table, stay 4B-aligned
            int off = o - sel;
            const ushort* bh = sel ? c1h : c0h;
            const ushort* bl = sel ? c1l : c0l;
            short8 ah = *(const short8*)&bh[off];
            short8 al = *(const short8*)&bl[off];
            acc[s] = __builtin_amdgcn_mfma_f32_16x16x32_bf16(ah, bfrag, acc[s], 0, 0, 0);
            acc[s] = __builtin_amdgcn_mfma_f32_16x16x32_bf16(al, bfrag, acc[s], 0, 0, 0);
        }
    }
    if (col < cols){
        const int nn = col >> 4, q0 = col & 15;      // local site, q
        #pragma unroll
        for (int s = 0; s < 3; ++s){
            #pragma unroll
            for (int r = 0; r < 4; ++r){
                int i = i0 + s*16 + quad*4 + r;      // D: row = quad*4 + reg
                U[(i*ns + nn)*256 + p*16 + q0] = (_Float16)acc[s][r];
            }
        }
    }
}

// ================= K4: v in registers + 3 fused EM iterations =================
__launch_bounds__(512, 2)
__global__ void k_em(const _Float16* __restrict__ U, const float* __restrict__ a_in,
                     const float* __restrict__ mpw, const float* __restrict__ mpb,
                     const float* __restrict__ csum,
                     const float* __restrict__ beta_u, const float* __restrict__ beta_a,
                     int n0, int ns, float* __restrict__ out)
{
    const int nl = blockIdx.x;          // local site in group
    const int n  = n0 + nl;             // global site
    const int t = threadIdx.x;          // 512
    const int Bc = t >> 4, p = t & 15;  // thread = (Bc, p)
    const int bs = n / L_, l = n % L_;

    __shared__ _Float16 us[2][16][256]; // staging chunk: [buf][ii][p*16+q]
    __shared__ float a_s[KKA_];
    __shared__ float d_s[16][33];
    __shared__ float rbuf[16][33];
    __shared__ float cst[32];

    // issue U chunk-0 loads first (longest latency)
    half4v ha, hb;
    {
        int u0 = t, u1 = t + 512;
        ha = *(const half4v*)&U[((u0>>6)*ns + nl)*256 + (u0&63)*4];
        hb = *(const half4v*)&U[((8 + (u1&511)/64)*ns + nl)*256 + (u1&63)*4];
    }

    // unfold this site's activation row
    for (int j = t; j < KKA_; j += 512){
        int kk = j >> 5, a = j & 31;
        int oy = l / OH_, ox = l % OH_;
        int y = oy*2 - 1 + kk/3, x = ox*2 - 1 + kk%3;
        float v = 0.f;
        if ((unsigned)y < 14u && (unsigned)x < 14u)
            v = a_in[((bs*A_ + a)*14 + y)*14 + x];
        a_s[j] = san(v, 0.f, 1e4f);
    }
    // per-thread weight row as packed fp16
    half2v w_h[8];
    #pragma unroll
    for (int k = 0; k < 8; ++k){
        w_h[k].x = (_Float16)mpw[t*16 + 2*k];
        w_h[k].y = (_Float16)mpw[t*16 + 2*k + 1];
    }
    const float vb = mpb[t] * csum[p];  // bias pushed through the filter
    const float bu = beta_u[Bc];
    const float ba = beta_a[Bc];

    // store chunk 0 into us[0]
    *(half4v*)&us[0][t>>6][(t&63)*4]       = ha;
    *(half4v*)&us[0][8 + (t>>6)][(t&63)*4] = hb;
    __syncthreads();                     // a_s + us[0] ready

    float S0tot = 0.f;
    for (int j = 0; j < KKA_; ++j) S0tot += a_s[j];   // broadcast reads

    // ---- phase 1: v once, banked to 144 packed-fp16 VGPRs; iter-1 moments ----
    half2v v_h[144];
    float S1 = 0.f, S2 = 0.f;
    #pragma unroll
    for (int ch = 0; ch < 18; ++ch){
        if (ch < 17){
            int base = (ch+1)*16;
            int u0 = t, u1 = t + 512;
            ha = *(const half4v*)&U[((base + (u0>>6))*ns + nl)*256 + (u0&63)*4];
            hb = *(const half4v*)&U[((base + 8 + (u0>>6))*ns + nl)*256 + (u1&63)*4];
        }
        #pragma unroll
        for (int k = 0; k < 8; ++k){     // i-pairs (2k, 2k+1)
            union { uint4 u4; half2v h2[4]; } A0, A1, B0, B1;
            A0.u4 = *(const uint4*)&us[ch&1][2*k][p*16];
            A1.u4 = *(const uint4*)&us[ch&1][2*k][p*16 + 8];
            B0.u4 = *(const uint4*)&us[ch&1][2*k+1][p*16];
            B1.u4 = *(const uint4*)&us[ch&1][2*k+1][p*16 + 8];
            float v0 = vb, v1 = vb;
            #pragma unroll
            for (int m = 0; m < 4; ++m){
                v0 = dot2acc(A0.h2[m], w_h[m],   v0);
                v0 = dot2acc(A1.h2[m], w_h[4+m], v0);
                v1 = dot2acc(B0.h2[m], w_h[m],   v1);
                v1 = dot2acc(B1.h2[m], w_h[4+m], v1);
            }
            float a0 = a_s[ch*16 + 2*k], a1 = a_s[ch*16 + 2*k + 1];
            S1 += a0*v0 + a1*v1;
            S2 += a0*v0*v0 + a1*v1*v1;
            half2v vh; vh.x = (_Float16)v0; vh.y = (_Float16)v1;
            v_h[ch*8 + k] = vh;
        }
        if (ch < 17){
            *(half4v*)&us[(ch+1)&1][t>>6][(t&63)*4]       = ha;
            *(half4v*)&us[(ch+1)&1][8 + (t>>6)][(t&63)*4] = hb;
        }
        __syncthreads();
    }

    // iter-1 m-step (r = 1/32 exactly); mu/i2s live in registers
    float mu_r, i2s_r;
    {
        const float rs  = S0tot * (1.0f/32.0f);
        const float inv = 1.0f / (rs + 1e-12f);
        const float S1r = S1 * (1.0f/32.0f), S2r = S2 * (1.0f/32.0f);
        mu_r = S1r * inv;
        const float sg  = fmaxf((S2r - 2.f*mu_r*S1r + mu_r*mu_r*rs) * inv, 0.f) + 1e-12f;
        i2s_r = 0.5f / sg;
        const float lg  = logf(sg);
        float cs = (bu + 0.5f*lg) * rs;
        float ls = lg + LOG_LN2PI;
        #pragma unroll
        for (int m = 1; m < 16; m <<= 1){ cs += __shfl_xor(cs, m, 16); ls += __shfl_xor(ls, m, 16); }
        const float aout = san(1.f/(1.f + expf(-LAM1*(ba - cs))), 1e-30f, 1.f);
        if (p == 0) cst[Bc] = logf(aout) - 0.5f*ls;
    }
    __syncthreads();

    // ---- iterations 2,3: pure-register v; 2 barriers per 16-i chunk ----
    const int b0 = p & 1, b1 = (p>>1)&1, b2 = (p>>2)&1, b3 = (p>>3)&1;
    float muF = 0.f, aF = 0.f;
    for (int it = 0; it < 2; ++it){
        const float lam = it ? LAM3 : LAM2;
        float T0 = 0.f, T1 = 0.f, T2 = 0.f;
        #pragma unroll
        for (int ch = 0; ch < 18; ++ch){
            float vc[16], e[16];
            #pragma unroll
            for (int k = 0; k < 8; ++k){
                half2v vh = v_h[ch*8 + k];
                vc[2*k]   = (float)vh.x;
                vc[2*k+1] = (float)vh.y;
            }
            #pragma unroll
            for (int s = 0; s < 16; ++s){
                float dv = vc[s] - mu_r;
                e[s] = dv*dv*i2s_r;
            }
            // butterfly transpose-reduce over the 16 p-lanes: lane p ends with d(ii=p)
            float e1[8], e2[4], e3[2], dfin;
            #pragma unroll
            for (int s = 0; s < 8; ++s){
                float a  = b0 ? e[2*s+1] : e[2*s];
                float sd = b0 ? e[2*s]   : e[2*s+1];
                e1[s] = a + __shfl_xor(sd, 1);
            }
            #pragma unroll
            for (int s = 0; s < 4; ++s){
                float a  = b1 ? e1[2*s+1] : e1[2*s];
                float sd = b1 ? e1[2*s]   : e1[2*s+1];
                e2[s] = a + __shfl_xor(sd, 2);
            }
            #pragma unroll
            for (int s = 0; s < 2; ++s){
                float a  = b2 ? e2[2*s+1] : e2[2*s];
                float sd = b2 ? e2[2*s]   : e2[2*s+1];
                e3[s] = a + __shfl_xor(sd, 4);
            }
            {
                float a  = b3 ? e3[1] : e3[0];
                float sd = b3 ? e3[0] : e3[1];
                dfin = a + __shfl_xor(sd, 8);
            }
            d_s[p][Bc] = dfin;
            __syncthreads();                   // (1) d_s ready
            {   // e-step softmax over B: thread -> (isub, Bce)
                const int isub = t >> 5, Bce = t & 31;
                float lnap = cst[Bce] - d_s[isub][Bce];
                float mx = lnap;
                #pragma unroll
                for (int m = 16; m >= 1; m >>= 1) mx = fmaxf(mx, __shfl_xor(mx, m));
                float ex = expf(lnap - mx);
                float sm = ex;
                #pragma unroll
                for (int m = 16; m >= 1; m >>= 1) sm += __shfl_xor(sm, m);
                rbuf[isub][Bce] = (ex / sm) * a_s[ch*16 + isub];
            }
            __syncthreads();                   // (2) rbuf ready
            #pragma unroll
            for (int s = 0; s < 16; ++s){
                float rr = rbuf[s][Bc];
                float tv = rr * vc[s];
                T0 += rr; T1 += tv; T2 += tv * vc[s];
            }
        }
        // m-step
        const float inv = 1.f/(T0 + 1e-12f);
        const float mu  = T1 * inv;
        const float sg  = fmaxf((T2 - 2.f*mu*T1 + mu*mu*T0) * inv, 0.f) + 1e-12f;
        const float lg  = logf(sg);
        float cs = (bu + 0.5f*lg) * T0;
        float ls = lg + LOG_LN2PI;
        #pragma unroll
        for (int m = 1; m < 16; m <<= 1){ cs += __shfl_xor(cs, m, 16); ls += __shfl_xor(ls, m, 16); }
        const float aout = san(1.f/(1.f + expf(-lam*(ba - cs))), 1e-30f, 1.f);
        if (it == 0){
            mu_r = mu; i2s_r = 0.5f/sg;
            if (p == 0) cst[Bc] = logf(aout) - 0.5f*ls;
            __syncthreads();                   // cst visible before next softmax
        } else { muF = mu; aF = aout; }
    }

    // ---- outputs (fp32): [a_fin 4*32*49][pose_out 4*512*49] ----
    if (p == 0) out[bs*(B_*L_) + Bc*L_ + l] = san(aF, 0.f, 1.f);
    out[6272 + (bs*512 + t)*L_ + l] = san(muF, -1e4f, 1e4f);
}

// ================= launch =================
extern "C" void kernel_launch(void* const* d_in, const int* in_sizes, int n_in,
                              void* d_out, int out_size, void* d_ws, size_t ws_size,
                              hipStream_t stream)
{
    // ALL device tensors are float32 (reference is jnp.float32 end-to-end).
    const float* a_in   = (const float*)d_in[0];
    const float* pose   = (const float*)d_in[1];
    const float* mpw    = (const float*)d_in[2];
    const float* mpb    = (const float*)d_in[3];
    const float* fw     = (const float*)d_in[4];
    // d_in[5..8] (ln_g, ln_b, spat_w, spat_bias) are provably dead: softmax over B of a
    // B-independent gate is exactly 1/B regardless of their values.
    const float* beta_u = (const float*)d_in[9];
    const float* beta_a = (const float*)d_in[10];
    float* out = (float*)d_out;

    // ---- ws layout (byte offsets) ----
    // csum [16] f32        @ 0      (64 B)
    // cpr  4x[16][592] u16 @ 256    (75776 B)
    // Xt   [cols][288] bf16 @ 76288 (576*cols B)
    // Ug   [288*ns*256] f16 @ 76288 + 9216*ns (147456*ns B)
    char* base = (char*)d_ws;
    float*  csum = (float*)(base + 0);
    ushort* cpr  = (ushort*)(base + 256);

    const int opts[] = {196, 98, 49, 28, 14, 7, 4, 2, 1};
    int ns = 1;
    for (int oi = 0; oi < 9; ++oi){
        size_t need = 76288u + (size_t)156672u * (size_t)opts[oi];
        if (need <= ws_size){ ns = opts[oi]; break; }
    }
    const int G = NSITE / ns;
    const int cols = ns * PS;
    __hip_bfloat16* Xt = (__hip_bfloat16*)(base + 76288);
    _Float16*       Ug = (_Float16*)(base + 76288 + (size_t)9216*ns);

    k_prep_c<<<18, 256, 0, stream>>>(fw, cpr, csum);
    for (int g = 0; g < G; ++g){
        const int n0 = g * ns;
        k_prep_x<<<(cols*KKA_ + 255)/256, 256, 0, stream>>>(pose, Xt, n0, cols);
        k_stageB<<<dim3((cols + 63)/64, 6, 16), 256, 0, stream>>>(cpr, Xt, Ug, cols, ns);
        k_em    <<<ns, 512, 0, stream>>>(Ug, a_in, mpw, mpb, csum, beta_u, beta_a, n0, ns, out);
    }
}